// Round 1
// 1196.011 us; speedup vs baseline: 2.3756x; 2.3756x over previous
//
#include <hip/hip_runtime.h>
#include <hip/hip_bf16.h>

#define Hh 256
#define Ss 64
#define Tt 64
#define Bb 32
#define Vv 32000

typedef __attribute__((ext_vector_type(8))) __bf16 bf16x8;
typedef __attribute__((ext_vector_type(8))) unsigned short u16x8;
typedef __attribute__((ext_vector_type(4))) float f32x4;

__device__ __forceinline__ float bf2f(unsigned short u) {
    union { unsigned int i; float f; } v;
    v.i = ((unsigned int)u) << 16;
    return v.f;
}

// ---------------------------------------------------------------------------
// P1: annProj[b,s,:] = annotations[b,s,:] @ W1[H:2H,:] + b1   (time-invariant)
// ---------------------------------------------------------------------------
__global__ __launch_bounds__(256) void annproj_kernel(
    const float* __restrict__ ann, const float* __restrict__ W1,
    const float* __restrict__ b1, float* __restrict__ annP)
{
    int row = blockIdx.x;          // b*S + s
    int tid = threadIdx.x;         // output column j
    __shared__ float sX[Hh];
    sX[tid] = ann[row * Hh + tid];
    __syncthreads();
    const float* w = W1 + Hh * Hh; // bottom half rows multiply annotations
    float acc = b1[tid];
#pragma unroll 4
    for (int i = 0; i < Hh; i++) acc = fmaf(sX[i], w[i * Hh + tid], acc);
    annP[row * Hh + tid] = acc;
}

// ---------------------------------------------------------------------------
// P2: embProj{Z,R,H}[b,t,:] = emb[tok[b,t]] @ Wi*[H:2H,:] + fused biases
// ---------------------------------------------------------------------------
__global__ __launch_bounds__(256) void embproj_kernel(
    const int* __restrict__ toks, const float* __restrict__ emb,
    const float* __restrict__ Wiz, const float* __restrict__ Wir,
    const float* __restrict__ Wih,
    const float* __restrict__ biz, const float* __restrict__ bir,
    const float* __restrict__ bih,
    const float* __restrict__ bhz, const float* __restrict__ bhr,
    float* __restrict__ eZ, float* __restrict__ eR, float* __restrict__ eH)
{
    int row = blockIdx.x;          // b*T + t
    int tid = threadIdx.x;
    __shared__ float sX[Hh];
    sX[tid] = emb[(size_t)toks[row] * Hh + tid];
    __syncthreads();
    const float* wz = Wiz + Hh * Hh;
    const float* wr = Wir + Hh * Hh;
    const float* wh = Wih + Hh * Hh;
    float az = biz[tid] + bhz[tid];
    float ar = bir[tid] + bhr[tid];
    float ah = bih[tid];
#pragma unroll 2
    for (int i = 0; i < Hh; i++) {
        float x = sX[i];
        int o = i * Hh + tid;
        az = fmaf(x, wz[o], az);
        ar = fmaf(x, wr[o], ar);
        ah = fmaf(x, wh[o], ah);
    }
    eZ[row * Hh + tid] = az;
    eR[row * Hh + tid] = ar;
    eH[row * Hh + tid] = ah;
}

// ---------------------------------------------------------------------------
// P3: WoutT[n][k] = bf16(Wout[k][n])
// ---------------------------------------------------------------------------
__global__ __launch_bounds__(256) void transpose_wout_kernel(
    const float* __restrict__ Wout, __hip_bfloat16* __restrict__ BT)
{
    __shared__ float tile[64][65];
    int n0 = blockIdx.x * 64, k0 = blockIdx.y * 64;
    int tid = threadIdx.x;
    int c = tid & 63, rb = tid >> 6;
#pragma unroll
    for (int it = 0; it < 16; it++) {
        int kk = it * 4 + rb;
        tile[kk][c] = Wout[(size_t)(k0 + kk) * Vv + n0 + c];
    }
    __syncthreads();
#pragma unroll
    for (int it = 0; it < 16; it++) {
        int nn = it * 4 + rb;
        BT[(size_t)(n0 + nn) * Hh + k0 + c] = __float2bfloat16(tile[c][nn]);
    }
}

// ---------------------------------------------------------------------------
// P4: pack 7 decoder weight matrices (256x256 fp32, column-major access) into
// bf16 [i/8][j][8] tiles so the decoder's weight loads are 16B/lane dwordx4.
// m: 0=W1top 1=Wiz(ctx) 2=Wir(ctx) 3=Wih(ctx) 4=Whz 5=Whr 6=Whh
// ---------------------------------------------------------------------------
__global__ __launch_bounds__(256) void pack_weights_kernel(
    const float* __restrict__ W1, const float* __restrict__ Wiz,
    const float* __restrict__ Wir, const float* __restrict__ Wih,
    const float* __restrict__ Whz, const float* __restrict__ Whr,
    const float* __restrict__ Whh, __hip_bfloat16* __restrict__ P)
{
    int c8 = blockIdx.x;           // i-chunk of 8 rows (0..31)
    int m  = blockIdx.y;           // matrix id
    int j  = threadIdx.x;          // column
    const float* src;
    switch (m) {
        case 0: src = W1;  break;
        case 1: src = Wiz; break;
        case 2: src = Wir; break;
        case 3: src = Wih; break;
        case 4: src = Whz; break;
        case 5: src = Whr; break;
        default: src = Whh; break;
    }
    __hip_bfloat16* dst = P + (size_t)m * (Hh * Hh) + ((size_t)c8 * Hh + j) * 8;
#pragma unroll
    for (int d = 0; d < 8; d++)
        dst[d] = __float2bfloat16(src[(c8 * 8 + d) * Hh + j]);
}

// ---------------------------------------------------------------------------
// K2: sequential decoder scan. One block per batch element, 1024 threads:
// every H=256 reduction is split 4-way over i-chunks (q = tid>>8) with an
// LDS partial tree. Weights are bf16-packed [i/8][j][8] -> each lane loads
// dwordx4 (8 weights), fully coalesced; h/ctx reads are wave-uniform b128
// broadcasts. 16 waves/CU for latency hiding (was 4).
// ---------------------------------------------------------------------------
__global__ __launch_bounds__(1024) void decoder_kernel(
    const float* __restrict__ ann, const float* __restrict__ h0,
    const __hip_bfloat16* __restrict__ PW,
    const float* __restrict__ W2, const float* __restrict__ b2,
    const float* __restrict__ bhh,
    const float* __restrict__ annP,
    const float* __restrict__ eZ, const float* __restrict__ eR,
    const float* __restrict__ eH,
    __hip_bfloat16* __restrict__ hidBf, float* __restrict__ attOut)
{
    const int b = blockIdx.x, tid = threadIdx.x;
    const int j = tid & 255;       // output column for A/D/E
    const int q = tid >> 8;        // i-chunk (64 i's each)

    __shared__ float sAnnP[Ss][Hh + 1];
    __shared__ float sAnnO[Ss][Hh + 1];
    __shared__ __align__(16) float sH[Hh];
    __shared__ __align__(16) float sHP[Hh];
    __shared__ __align__(16) float sCtx[Hh];
    __shared__ float sW2[Hh];
    __shared__ float sAw[Ss];
    __shared__ float sRedB[16][Ss];
    __shared__ float sRed[16][Hh];

    const u16x8* pW1  = (const u16x8*)(PW);
    const u16x8* pWiz = (const u16x8*)(PW + 1 * 65536);
    const u16x8* pWir = (const u16x8*)(PW + 2 * 65536);
    const u16x8* pWih = (const u16x8*)(PW + 3 * 65536);
    const u16x8* pWhz = (const u16x8*)(PW + 4 * 65536);
    const u16x8* pWhr = (const u16x8*)(PW + 5 * 65536);
    const u16x8* pWhh = (const u16x8*)(PW + 6 * 65536);

    for (int idx = tid; idx < Ss * Hh; idx += 1024) {
        int s = idx >> 8, c = idx & 255;
        sAnnP[s][c] = annP[((size_t)b * Ss + s) * Hh + c];
        sAnnO[s][c] = ann [((size_t)b * Ss + s) * Hh + c];
    }
    if (tid < Hh) { sH[tid] = h0[b * Hh + tid]; sW2[tid] = W2[tid]; }
    const float bhhj = (tid < Hh) ? bhh[tid] : 0.f;
    const float b2s = b2[0];
    const int sphase = tid & 63, cphase = tid >> 6;  // score phase mapping
    __syncthreads();

    const f32x4* sH4 = (const f32x4*)sH;
    const f32x4* sC4 = (const f32x4*)sCtx;

    for (int t = 0; t < Tt; t++) {
        const int rowt = b * Tt + t;
        // hoist eZ/eR/eH loads: latency hides under phases A-D
        float ez = 0.f, er = 0.f, eh = 0.f;
        if (tid < Hh) {
            ez = eZ[(size_t)rowt * Hh + tid];
            er = eR[(size_t)rowt * Hh + tid];
            eh = eH[(size_t)rowt * Hh + tid];
        }

        // --- A: hProj partials, 4-way i-split
        float pa = 0.f;
#pragma unroll 4
        for (int c = 0; c < 8; c++) {
            int c8 = q * 8 + c;
            u16x8 w = pW1[c8 * Hh + j];
            f32x4 ha = sH4[c8 * 2], hb = sH4[c8 * 2 + 1];
#pragma unroll
            for (int d = 0; d < 4; d++) {
                pa = fmaf(bf2f(w[d]),     ha[d], pa);
                pa = fmaf(bf2f(w[d + 4]), hb[d], pa);
            }
        }
        sRed[q][j] = pa;
        __syncthreads();
        if (tid < Hh)
            sHP[tid] = sRed[0][tid] + sRed[1][tid] + sRed[2][tid] + sRed[3][tid];
        __syncthreads();

        // --- B: u[s] partials over 16-column chunks
        float pb = 0.f;
#pragma unroll
        for (int k = 0; k < 16; k++) {
            int jj = cphase * 16 + k;
            float v = sHP[jj] + sAnnP[sphase][jj];
            pb = fmaf(sW2[jj], fmaxf(v, 0.f), pb);
        }
        sRedB[cphase][sphase] = pb;
        __syncthreads();

        // --- C: softmax over s (wave 0) + attentions write
        if (tid < 64) {
            float u = b2s;
#pragma unroll
            for (int k = 0; k < 16; k++) u += sRedB[k][tid];
            float m = u;
#pragma unroll
            for (int off = 32; off; off >>= 1) m = fmaxf(m, __shfl_xor(m, off));
            float e = __expf(u - m);
            float ssum = e;
#pragma unroll
            for (int off = 32; off; off >>= 1) ssum += __shfl_xor(ssum, off);
            float aw = e / ssum;
            sAw[tid] = aw;
            attOut[((size_t)b * Ss + tid) * Tt + t] = aw;
        }
        __syncthreads();

        // --- D: context partials, 4-way s-split
        float pd = 0.f;
#pragma unroll
        for (int k = 0; k < 16; k++) {
            int s2 = q * 16 + k;
            pd = fmaf(sAw[s2], sAnnO[s2][j], pd);
        }
        sRed[q][j] = pd;
        __syncthreads();
        if (tid < Hh)
            sCtx[tid] = sRed[0][tid] + sRed[1][tid] + sRed[2][tid] + sRed[3][tid];
        __syncthreads();

        // --- E: 6 fused matvec streams, 4-way i-split, bf16 packed weights
        float az = 0.f, ar = 0.f, ah = 0.f, ahh = 0.f;
#pragma unroll 2
        for (int c = 0; c < 8; c++) {
            int c8 = q * 8 + c;
            int widx = c8 * Hh + j;
            u16x8 wz = pWiz[widx], wr = pWir[widx], wh = pWih[widx];
            u16x8 vz = pWhz[widx], vr = pWhr[widx], vh = pWhh[widx];
            f32x4 ca = sC4[c8 * 2], cb = sC4[c8 * 2 + 1];
            f32x4 ga = sH4[c8 * 2], gb = sH4[c8 * 2 + 1];
#pragma unroll
            for (int d = 0; d < 4; d++) {
                float cv = ca[d], hv = ga[d];
                az  = fmaf(bf2f(wz[d]), cv, az);
                az  = fmaf(bf2f(vz[d]), hv, az);
                ar  = fmaf(bf2f(wr[d]), cv, ar);
                ar  = fmaf(bf2f(vr[d]), hv, ar);
                ah  = fmaf(bf2f(wh[d]), cv, ah);
                ahh = fmaf(bf2f(vh[d]), hv, ahh);
            }
#pragma unroll
            for (int d = 0; d < 4; d++) {
                float cv = cb[d], hv = gb[d];
                az  = fmaf(bf2f(wz[d + 4]), cv, az);
                az  = fmaf(bf2f(vz[d + 4]), hv, az);
                ar  = fmaf(bf2f(wr[d + 4]), cv, ar);
                ar  = fmaf(bf2f(vr[d + 4]), hv, ar);
                ah  = fmaf(bf2f(wh[d + 4]), cv, ah);
                ahh = fmaf(bf2f(vh[d + 4]), hv, ahh);
            }
        }
        sRed[q * 4 + 0][j] = az;
        sRed[q * 4 + 1][j] = ar;
        sRed[q * 4 + 2][j] = ah;
        sRed[q * 4 + 3][j] = ahh;
        __syncthreads();

        // --- F: gate finalize + h update (threads 0..255)
        if (tid < Hh) {
            float accZ  = ez + sRed[0][tid] + sRed[4][tid] + sRed[8][tid]  + sRed[12][tid];
            float accR  = er + sRed[1][tid] + sRed[5][tid] + sRed[9][tid]  + sRed[13][tid];
            float accH  = eh + sRed[2][tid] + sRed[6][tid] + sRed[10][tid] + sRed[14][tid];
            float accHH =      sRed[3][tid] + sRed[7][tid] + sRed[11][tid] + sRed[15][tid];
            float z = 1.f / (1.f + __expf(-accZ));
            float r = 1.f / (1.f + __expf(-accR));
            float g = tanhf(accH + r * (accHH + bhhj));
            float hnew = (1.f - z) * g + z * sH[tid];
            sH[tid] = hnew;   // safe: all E-phase reads of sH happened pre-barrier
            hidBf[(size_t)rowt * Hh + tid] = __float2bfloat16(hnew);
        }
        __syncthreads();
    }
}

// ---------------------------------------------------------------------------
// K3: output = hiddens(bf16) @ WoutT^T(bf16) + bout, fp32 out.
// ---------------------------------------------------------------------------
__global__ __launch_bounds__(256) void out_gemm_kernel(
    const __hip_bfloat16* __restrict__ A,   // (2048,256)
    const __hip_bfloat16* __restrict__ BT,  // (32000,256)
    const float* __restrict__ bout,
    float* __restrict__ C)                  // (2048,32000)
{
    int n0 = blockIdx.x * 128, m0 = blockIdx.y * 128;
    int tid = threadIdx.x;
    int w = tid >> 6, l = tid & 63;
    int wm = (w >> 1) * 64, wn = (w & 1) * 64;
    int quad = l >> 4, l15 = l & 15;

    const __hip_bfloat16* Arow = A + (size_t)(m0 + wm + l15) * Hh + quad * 8;
    const __hip_bfloat16* Brow = BT + (size_t)(n0 + wn + l15) * Hh + quad * 8;

    f32x4 acc[4][4] = {};
#pragma unroll
    for (int kk = 0; kk < 8; kk++) {
        bf16x8 af[4], bfv[4];
#pragma unroll
        for (int mi = 0; mi < 4; mi++)
            af[mi] = *(const bf16x8*)(Arow + mi * 16 * Hh + kk * 32);
#pragma unroll
        for (int ni = 0; ni < 4; ni++)
            bfv[ni] = *(const bf16x8*)(Brow + ni * 16 * Hh + kk * 32);
#pragma unroll
        for (int mi = 0; mi < 4; mi++)
#pragma unroll
            for (int ni = 0; ni < 4; ni++)
                acc[mi][ni] = __builtin_amdgcn_mfma_f32_16x16x32_bf16(
                    af[mi], bfv[ni], acc[mi][ni], 0, 0, 0);
    }
#pragma unroll
    for (int ni = 0; ni < 4; ni++) {
        int col = n0 + wn + ni * 16 + l15;
        float bo = bout[col];
#pragma unroll
        for (int mi = 0; mi < 4; mi++) {
            int rowb = m0 + wm + mi * 16 + quad * 4;
#pragma unroll
            for (int r = 0; r < 4; r++)
                C[(size_t)(rowb + r) * Vv + col] = acc[mi][ni][r] + bo;
        }
    }
}

// ---------------------------------------------------------------------------
extern "C" void kernel_launch(void* const* d_in, const int* in_sizes, int n_in,
                              void* d_out, int out_size, void* d_ws, size_t ws_size,
                              hipStream_t stream) {
    const int*   toks = (const int*)d_in[0];
    const float* ann  = (const float*)d_in[1];
    const float* h0   = (const float*)d_in[2];
    const float* emb  = (const float*)d_in[3];
    const float* W1   = (const float*)d_in[4];
    const float* b1   = (const float*)d_in[5];
    const float* W2   = (const float*)d_in[6];
    const float* b2   = (const float*)d_in[7];
    const float* Wiz  = (const float*)d_in[8];
    const float* biz  = (const float*)d_in[9];
    const float* Wir  = (const float*)d_in[10];
    const float* bir  = (const float*)d_in[11];
    const float* Wih  = (const float*)d_in[12];
    const float* bih  = (const float*)d_in[13];
    const float* Whz  = (const float*)d_in[14];
    const float* bhz  = (const float*)d_in[15];
    const float* Whr  = (const float*)d_in[16];
    const float* bhr  = (const float*)d_in[17];
    const float* Whh  = (const float*)d_in[18];
    const float* bhh  = (const float*)d_in[19];
    const float* Wout = (const float*)d_in[20];
    const float* bout = (const float*)d_in[21];

    float* out    = (float*)d_out;
    float* attOut = out + (size_t)Bb * Tt * Vv;   // attentions after output

    float* ws   = (float*)d_ws;
    float* annP = ws;                               // 524288 f32
    float* eZ   = ws + 524288;
    float* eR   = ws + 1048576;
    float* eH   = ws + 1572864;
    __hip_bfloat16* hidBf = (__hip_bfloat16*)(ws + 2097152);  // 524288 bf16
    __hip_bfloat16* WoutT = (__hip_bfloat16*)(ws + 2359296);  // 8192000 bf16
    __hip_bfloat16* PW    = (__hip_bfloat16*)(ws + 6455296);  // 458752 bf16 packed weights

    annproj_kernel<<<dim3(Bb * Ss), dim3(256), 0, stream>>>(ann, W1, b1, annP);
    embproj_kernel<<<dim3(Bb * Tt), dim3(256), 0, stream>>>(
        toks, emb, Wiz, Wir, Wih, biz, bir, bih, bhz, bhr, eZ, eR, eH);
    transpose_wout_kernel<<<dim3(Vv / 64, Hh / 64), dim3(256), 0, stream>>>(Wout, WoutT);
    pack_weights_kernel<<<dim3(32, 7), dim3(256), 0, stream>>>(
        W1, Wiz, Wir, Wih, Whz, Whr, Whh, PW);
    decoder_kernel<<<dim3(Bb), dim3(1024), 0, stream>>>(
        ann, h0, PW, W2, b2, bhh, annP, eZ, eR, eH, hidBf, attOut);
    out_gemm_kernel<<<dim3(Vv / 128, (Bb * Tt) / 128), dim3(256), 0, stream>>>(
        hidBf, WoutT, bout, out);
}